// Round 2
// baseline (244.269 us; speedup 1.0000x reference)
//
#include <hip/hip_runtime.h>
#include <hip/hip_bf16.h>

#define Bsz 256
#define Tn 2048
#define QD 1024
#define AD 128
#define DCn 8
#define DKn 21
#define PLn 11
#define GN (DCn * DKn)   // 168
#define CT 512           // t-chunk per phase
#define XS 24            // X_lds stride in halfs (48 B -> balanced banks)
#define NCH (Tn / CT)    // 4

typedef _Float16 f16x8 __attribute__((ext_vector_type(8)));
typedef float f32x4 __attribute__((ext_vector_type(4)));

// ---------------------------------------------------------------------------
// Kernel 1: per-sample dynamic filters  G[b] = tanh(q W^T + b) V^T  -> d_ws
// 512 threads (8 waves) per b for latency hiding; split FMA chains.
// ---------------------------------------------------------------------------
__global__ __launch_bounds__(512) void g_kernel(
    const float* __restrict__ query, const float* __restrict__ W_w,
    const float* __restrict__ W_b, const float* __restrict__ V_w,
    float* __restrict__ G_ws)
{
    __shared__ float h_lds[AD];
    const int b    = blockIdx.x;
    const int tid  = threadIdx.x;
    const int w    = tid >> 6;      // 0..7
    const int lane = tid & 63;

    const float4* q4 = (const float4*)(query + b * QD);
    float4 q0 = q4[lane];
    float4 q1 = q4[64 + lane];
    float4 q2 = q4[128 + lane];
    float4 q3 = q4[192 + lane];

    #pragma unroll 2
    for (int i = 0; i < 16; ++i) {
        int a = w * 16 + i;
        const float4* w4 = (const float4*)(W_w + a * QD);
        float4 x0 = w4[lane];
        float4 x1 = w4[64 + lane];
        float4 x2 = w4[128 + lane];
        float4 x3 = w4[192 + lane];
        float accA = 0.f, accB = 0.f;
        accA = fmaf(q0.x, x0.x, fmaf(q0.y, x0.y, fmaf(q0.z, x0.z, fmaf(q0.w, x0.w, accA))));
        accB = fmaf(q1.x, x1.x, fmaf(q1.y, x1.y, fmaf(q1.z, x1.z, fmaf(q1.w, x1.w, accB))));
        accA = fmaf(q2.x, x2.x, fmaf(q2.y, x2.y, fmaf(q2.z, x2.z, fmaf(q2.w, x2.w, accA))));
        accB = fmaf(q3.x, x3.x, fmaf(q3.y, x3.y, fmaf(q3.z, x3.z, fmaf(q3.w, x3.w, accB))));
        float acc = accA + accB;
        #pragma unroll
        for (int off = 32; off; off >>= 1) acc += __shfl_xor(acc, off);
        if (lane == 0) h_lds[a] = tanhf(acc + W_b[a]);
    }
    __syncthreads();

    for (int r = w; r < GN; r += 8) {
        float acc = fmaf(h_lds[lane], V_w[r * AD + lane],
                         h_lds[64 + lane] * V_w[r * AD + 64 + lane]);
        #pragma unroll
        for (int off = 32; off; off >>= 1) acc += __shfl_xor(acc, off);
        if (lane == 0) G_ws[b * GN + r] = acc;
    }
}

// ---------------------------------------------------------------------------
// Kernel 2: conv (fp32 VALU) -> X[t,16] f16 in LDS -> MFMA 16->128 projection
// -> fused tanh*v reduce -> s = clip(prior)*exp(e_inner) -> block softmax.
// One 1024-thread block per b; 4 chunks of 512 t.
// MFMA layouts (verified, guide §3/§5): A[m=lane&15][k=quad*8+j],
// B[k=quad*8+j][n=lane&15], D col=lane&15 row=quad*4+reg. K=16 real, quads
// 2..3 zero.
// ---------------------------------------------------------------------------
__global__ __launch_bounds__(1024) void e_kernel(
    const float* __restrict__ align, const float* __restrict__ P,
    const float* __restrict__ F_w, const float* __restrict__ U_w,
    const float* __restrict__ T_w, const float* __restrict__ T_b,
    const float* __restrict__ v_w, const float* __restrict__ G_ws,
    float* __restrict__ out)
{
    __shared__ float al[Tn + 20];
    __shared__ float pcb[CT];
    __shared__ _Float16 X[CT * XS];
    __shared__ float sden[Tn];
    __shared__ float red[16];
    __shared__ float bc;

    const int b    = blockIdx.x;
    const int tid  = threadIdx.x;
    const int lane = tid & 63;
    const int wid  = tid >> 6;
    const int l15  = lane & 15;
    const int quad = lane >> 4;

    // stage padded alignment row (pad = 10 zeros each side)
    for (int i = tid; i < Tn + 20; i += 1024) {
        int s = i - 10;
        al[i] = (s >= 0 && s < Tn) ? align[b * Tn + s] : 0.f;
    }

    // B fragments: W'[a][c] = [U_w | T_w] row a, f16. quad0 -> c 0..7 (U),
    // quad1 -> c 8..15 (T), quads 2,3 -> zero. Also v[a], T_b[a] per lane.
    f16x8 Bf[8];
    float vv[8], tb[8];
    #pragma unroll
    for (int n = 0; n < 8; ++n) {
        int a = n * 16 + l15;
        f16x8 bf = {};
        const float* src = (quad == 0) ? (U_w + a * 8) : (T_w + a * 8);
        if (quad < 2) {
            float4 lo = ((const float4*)src)[0];
            float4 hi = ((const float4*)src)[1];
            bf[0] = (_Float16)lo.x; bf[1] = (_Float16)lo.y;
            bf[2] = (_Float16)lo.z; bf[3] = (_Float16)lo.w;
            bf[4] = (_Float16)hi.x; bf[5] = (_Float16)hi.y;
            bf[6] = (_Float16)hi.z; bf[7] = (_Float16)hi.w;
        }
        Bf[n] = bf;
        vv[n] = v_w[a];
        tb[n] = T_b[a];
    }
    __syncthreads();

    const float* Gp = G_ws + b * GN;
    const int tl = tid & (CT - 1);   // 0..511
    const int hg = tid >> 9;         // 0: f-channels, 1: g-channels
    float wsum = 0.f;

    for (int ch = 0; ch < NCH; ++ch) {
        // ---- phase 1: conv for CT t's (two thread-halves: f vs g) ----
        {
            const int t = ch * CT + tl;
            float w0[DKn];
            #pragma unroll
            for (int k = 0; k < DKn; ++k) w0[k] = al[t + k];
            const float* wt = hg ? Gp : F_w;   // wave-uniform pointer
            f16x8 xv;
            #pragma unroll
            for (int c = 0; c < DCn; ++c) {
                float acc = 0.f;
                #pragma unroll
                for (int k = 0; k < DKn; ++k) acc = fmaf(w0[k], wt[c * DKn + k], acc);
                xv[c] = (_Float16)acc;
            }
            *(f16x8*)&X[tl * XS + hg * 8] = xv;
            if (hg == 0) {
                float pr = 0.f;
                #pragma unroll
                for (int k = 0; k < PLn; ++k) pr = fmaf(w0[k], P[k], pr);
                pcb[tl] = fmaxf(pr, 1e-6f);     // exp(e)=pc*exp(e_inner): no log needed
            }
        }
        __syncthreads();

        // ---- phase 2: 32 local m-tiles, 2 per wave ----
        #pragma unroll
        for (int i = 0; i < 2; ++i) {
            const int mtl  = wid * 2 + i;
            const int trow = mtl * 16 + l15;
            f16x8 Af = {};
            if (quad < 2) Af = *(const f16x8*)&X[trow * XS + quad * 8];
            float es0 = 0.f, es1 = 0.f, es2 = 0.f, es3 = 0.f;
            #pragma unroll
            for (int n = 0; n < 8; ++n) {
                f32x4 z = {};
                f32x4 d = __builtin_amdgcn_mfma_f32_16x16x32_f16(Af, Bf[n], z, 0, 0, 0);
                float x0 = d[0] + tb[n], x1 = d[1] + tb[n];
                float x2 = d[2] + tb[n], x3 = d[3] + tb[n];
                // tanh(x) = 1 - 2/(exp(2x)+1)
                float q0 = __expf(2.f * x0), q1 = __expf(2.f * x1);
                float q2 = __expf(2.f * x2), q3 = __expf(2.f * x3);
                float r0 = __builtin_amdgcn_rcpf(q0 + 1.f);
                float r1 = __builtin_amdgcn_rcpf(q1 + 1.f);
                float r2 = __builtin_amdgcn_rcpf(q2 + 1.f);
                float r3 = __builtin_amdgcn_rcpf(q3 + 1.f);
                es0 = fmaf(vv[n], fmaf(-2.f, r0, 1.f), es0);
                es1 = fmaf(vv[n], fmaf(-2.f, r1, 1.f), es1);
                es2 = fmaf(vv[n], fmaf(-2.f, r2, 1.f), es2);
                es3 = fmaf(vv[n], fmaf(-2.f, r3, 1.f), es3);
            }
            // reduce over the 16 cols (a within tile); stays inside quad group
            #pragma unroll
            for (int off = 1; off <= 8; off <<= 1) {
                es0 += __shfl_xor(es0, off);
                es1 += __shfl_xor(es1, off);
                es2 += __shfl_xor(es2, off);
                es3 += __shfl_xor(es3, off);
            }
            if (l15 < 4) {
                float ev = (l15 == 0) ? es0 : (l15 == 1) ? es1 : (l15 == 2) ? es2 : es3;
                int tt2 = mtl * 16 + quad * 4 + l15;
                float sv = pcb[tt2] * __expf(ev);
                sden[ch * CT + tt2] = sv;
                wsum += sv;
            }
        }
        __syncthreads();   // X/pcb reused next chunk
    }

    // ---- block sum + normalize ----
    #pragma unroll
    for (int off = 32; off; off >>= 1) wsum += __shfl_xor(wsum, off);
    if (lane == 0) red[wid] = wsum;
    __syncthreads();
    if (wid == 0) {
        float ss = (lane < 16) ? red[lane] : 0.f;
        #pragma unroll
        for (int off = 8; off; off >>= 1) ss += __shfl_xor(ss, off);
        if (lane == 0) bc = ss;
    }
    __syncthreads();
    const float inv = 1.f / bc;
    out[b * Tn + tid]        = sden[tid] * inv;
    out[b * Tn + tid + 1024] = sden[tid + 1024] * inv;
}

// ---------------------------------------------------------------------------
extern "C" void kernel_launch(void* const* d_in, const int* in_sizes, int n_in,
                              void* d_out, int out_size, void* d_ws, size_t ws_size,
                              hipStream_t stream) {
    const float* query = (const float*)d_in[0];
    const float* align = (const float*)d_in[1];
    const float* P     = (const float*)d_in[2];
    const float* W_w   = (const float*)d_in[3];
    const float* W_b   = (const float*)d_in[4];
    const float* V_w   = (const float*)d_in[5];
    const float* F_w   = (const float*)d_in[6];
    const float* U_w   = (const float*)d_in[7];
    const float* T_w   = (const float*)d_in[8];
    const float* T_b   = (const float*)d_in[9];
    const float* v_w   = (const float*)d_in[10];
    float* out  = (float*)d_out;
    float* G_ws = (float*)d_ws;   // 256*168 floats

    g_kernel<<<Bsz, 512, 0, stream>>>(query, W_w, W_b, V_w, G_ws);
    e_kernel<<<Bsz, 1024, 0, stream>>>(align, P, F_w, U_w, T_w, T_b, v_w, G_ws, out);
}

// Round 3
// 132.624 us; speedup vs baseline: 1.8418x; 1.8418x over previous
//
#include <hip/hip_runtime.h>
#include <hip/hip_bf16.h>

#define Bsz 256
#define Tn 2048
#define QD 1024
#define AD 128
#define DCn 8
#define DKn 21
#define PLn 11
#define GN (DCn * DKn)   // 168
#define CT 512           // t-chunk per phase
#define XS 24            // X_lds stride in halfs (48 B -> balanced banks)
#define NCH (Tn / CT)    // 4

typedef _Float16 f16x8 __attribute__((ext_vector_type(8)));
typedef float f32x4 __attribute__((ext_vector_type(4)));

// ---------------------------------------------------------------------------
// Kernel 1: per-sample dynamic filters  G[b] = tanh(q W^T + b) V^T  -> d_ws
// ---------------------------------------------------------------------------
__global__ __launch_bounds__(512) void g_kernel(
    const float* __restrict__ query, const float* __restrict__ W_w,
    const float* __restrict__ W_b, const float* __restrict__ V_w,
    float* __restrict__ G_ws)
{
    __shared__ float h_lds[AD];
    const int b    = blockIdx.x;
    const int tid  = threadIdx.x;
    const int w    = tid >> 6;      // 0..7
    const int lane = tid & 63;

    const float4* q4 = (const float4*)(query + b * QD);
    float4 q0 = q4[lane];
    float4 q1 = q4[64 + lane];
    float4 q2 = q4[128 + lane];
    float4 q3 = q4[192 + lane];

    #pragma unroll 2
    for (int i = 0; i < 16; ++i) {
        int a = w * 16 + i;
        const float4* w4 = (const float4*)(W_w + a * QD);
        float4 x0 = w4[lane];
        float4 x1 = w4[64 + lane];
        float4 x2 = w4[128 + lane];
        float4 x3 = w4[192 + lane];
        float accA = 0.f, accB = 0.f;
        accA = fmaf(q0.x, x0.x, fmaf(q0.y, x0.y, fmaf(q0.z, x0.z, fmaf(q0.w, x0.w, accA))));
        accB = fmaf(q1.x, x1.x, fmaf(q1.y, x1.y, fmaf(q1.z, x1.z, fmaf(q1.w, x1.w, accB))));
        accA = fmaf(q2.x, x2.x, fmaf(q2.y, x2.y, fmaf(q2.z, x2.z, fmaf(q2.w, x2.w, accA))));
        accB = fmaf(q3.x, x3.x, fmaf(q3.y, x3.y, fmaf(q3.z, x3.z, fmaf(q3.w, x3.w, accB))));
        float acc = accA + accB;
        #pragma unroll
        for (int off = 32; off; off >>= 1) acc += __shfl_xor(acc, off);
        if (lane == 0) h_lds[a] = tanhf(acc + W_b[a]);
    }
    __syncthreads();

    for (int r = w; r < GN; r += 8) {
        float acc = fmaf(h_lds[lane], V_w[r * AD + lane],
                         h_lds[64 + lane] * V_w[r * AD + 64 + lane]);
        #pragma unroll
        for (int off = 32; off; off >>= 1) acc += __shfl_xor(acc, off);
        if (lane == 0) G_ws[b * GN + r] = acc;
    }
}

// ---------------------------------------------------------------------------
// Kernel 2: conv (fp32) -> X[t,16] f16 in LDS -> MFMA 16->128 projection
// -> fused tanh*v reduce -> s = clip(prior)*exp(e_inner) -> block softmax.
// One 1024-thread block per b; 4 chunks of 512 t.
// __launch_bounds__(1024, 4): a 1024-thread block is 4 waves/SIMD resident,
// so budget VGPRs for exactly that -> 128 regs, no scratch spill (R2's 64-reg
// cap spilled ~500 MB to scratch and went memory-bound).
// ---------------------------------------------------------------------------
__global__ __launch_bounds__(1024, 4) void e_kernel(
    const float* __restrict__ align, const float* __restrict__ P,
    const float* __restrict__ F_w, const float* __restrict__ U_w,
    const float* __restrict__ T_w, const float* __restrict__ T_b,
    const float* __restrict__ v_w, const float* __restrict__ G_ws,
    float* __restrict__ out)
{
    __shared__ float al[Tn + 20];
    __shared__ float pcb[CT];
    __shared__ _Float16 X[CT * XS];
    __shared__ float sden[Tn];
    __shared__ float red[16];
    __shared__ float bc;

    const int b    = blockIdx.x;
    const int tid  = threadIdx.x;
    const int lane = tid & 63;
    const int wid  = tid >> 6;
    const int l15  = lane & 15;
    const int quad = lane >> 4;

    // stage padded alignment row (pad = 10 zeros each side)
    for (int i = tid; i < Tn + 20; i += 1024) {
        int s = i - 10;
        al[i] = (s >= 0 && s < Tn) ? align[b * Tn + s] : 0.f;
    }

    // B fragments: W'[a][c] = [U_w | T_w] row a, f16. quad0 -> c 0..7 (U),
    // quad1 -> c 8..15 (T), quads 2,3 -> zero. Also v[a], T_b[a] per lane.
    f16x8 Bf[8];
    float vv[8], tb[8];
    #pragma unroll
    for (int n = 0; n < 8; ++n) {
        int a = n * 16 + l15;
        f16x8 bf = {};
        const float* src = (quad == 0) ? (U_w + a * 8) : (T_w + a * 8);
        if (quad < 2) {
            float4 lo = ((const float4*)src)[0];
            float4 hi = ((const float4*)src)[1];
            bf[0] = (_Float16)lo.x; bf[1] = (_Float16)lo.y;
            bf[2] = (_Float16)lo.z; bf[3] = (_Float16)lo.w;
            bf[4] = (_Float16)hi.x; bf[5] = (_Float16)hi.y;
            bf[6] = (_Float16)hi.z; bf[7] = (_Float16)hi.w;
        }
        Bf[n] = bf;
        vv[n] = v_w[a];
        tb[n] = T_b[a];
    }
    __syncthreads();

    const int tl  = tid & (CT - 1);                       // 0..511
    const int hgu = __builtin_amdgcn_readfirstlane(tid) >> 9;  // wave-uniform half id
    const float* wt = hgu ? (G_ws + b * GN) : F_w;        // scalar weight pointer
    float wsum = 0.f;

    for (int ch = 0; ch < NCH; ++ch) {
        // ---- phase 1: conv for CT t's (two thread-halves: f vs g) ----
        {
            const int t = ch * CT + tl;
            float w0[DKn];
            #pragma unroll
            for (int k = 0; k < DKn; ++k) w0[k] = al[t + k];
            f16x8 xv;
            #pragma unroll
            for (int c = 0; c < DCn; ++c) {
                float acc = 0.f;
                #pragma unroll
                for (int k = 0; k < DKn; ++k) acc = fmaf(w0[k], wt[c * DKn + k], acc);
                xv[c] = (_Float16)acc;
            }
            *(f16x8*)&X[tl * XS + hgu * 8] = xv;
            if (hgu == 0) {
                float pr = 0.f;
                #pragma unroll
                for (int k = 0; k < PLn; ++k) pr = fmaf(w0[k], P[k], pr);
                pcb[tl] = fmaxf(pr, 1e-6f);   // exp(e)=pc*exp(e_inner): no log needed
            }
        }
        __syncthreads();

        // ---- phase 2: 32 local m-tiles, 2 per wave ----
        #pragma unroll
        for (int i = 0; i < 2; ++i) {
            const int mtl  = wid * 2 + i;
            const int trow = mtl * 16 + l15;
            f16x8 Af = {};
            if (quad < 2) Af = *(const f16x8*)&X[trow * XS + quad * 8];
            float es0 = 0.f, es1 = 0.f, es2 = 0.f, es3 = 0.f;
            #pragma unroll
            for (int n = 0; n < 8; ++n) {
                f32x4 z = {};
                f32x4 d = __builtin_amdgcn_mfma_f32_16x16x32_f16(Af, Bf[n], z, 0, 0, 0);
                float x0 = d[0] + tb[n], x1 = d[1] + tb[n];
                float x2 = d[2] + tb[n], x3 = d[3] + tb[n];
                // tanh(x) = 1 - 2/(exp(2x)+1)
                float q0 = __expf(2.f * x0), q1 = __expf(2.f * x1);
                float q2 = __expf(2.f * x2), q3 = __expf(2.f * x3);
                float r0 = __builtin_amdgcn_rcpf(q0 + 1.f);
                float r1 = __builtin_amdgcn_rcpf(q1 + 1.f);
                float r2 = __builtin_amdgcn_rcpf(q2 + 1.f);
                float r3 = __builtin_amdgcn_rcpf(q3 + 1.f);
                es0 = fmaf(vv[n], fmaf(-2.f, r0, 1.f), es0);
                es1 = fmaf(vv[n], fmaf(-2.f, r1, 1.f), es1);
                es2 = fmaf(vv[n], fmaf(-2.f, r2, 1.f), es2);
                es3 = fmaf(vv[n], fmaf(-2.f, r3, 1.f), es3);
            }
            // reduce over the 16 cols (a within tile); stays inside quad group
            #pragma unroll
            for (int off = 1; off <= 8; off <<= 1) {
                es0 += __shfl_xor(es0, off);
                es1 += __shfl_xor(es1, off);
                es2 += __shfl_xor(es2, off);
                es3 += __shfl_xor(es3, off);
            }
            if (l15 < 4) {
                float ev = (l15 == 0) ? es0 : (l15 == 1) ? es1 : (l15 == 2) ? es2 : es3;
                int tt2 = mtl * 16 + quad * 4 + l15;
                float sv = pcb[tt2] * __expf(ev);
                sden[ch * CT + tt2] = sv;
                wsum += sv;
            }
        }
        __syncthreads();   // X/pcb reused next chunk
    }

    // ---- block sum + normalize ----
    #pragma unroll
    for (int off = 32; off; off >>= 1) wsum += __shfl_xor(wsum, off);
    if (lane == 0) red[wid] = wsum;
    __syncthreads();
    if (wid == 0) {
        float ss = (lane < 16) ? red[lane] : 0.f;
        #pragma unroll
        for (int off = 8; off; off >>= 1) ss += __shfl_xor(ss, off);
        if (lane == 0) bc = ss;
    }
    __syncthreads();
    const float inv = 1.f / bc;
    out[b * Tn + tid]        = sden[tid] * inv;
    out[b * Tn + tid + 1024] = sden[tid + 1024] * inv;
}

// ---------------------------------------------------------------------------
extern "C" void kernel_launch(void* const* d_in, const int* in_sizes, int n_in,
                              void* d_out, int out_size, void* d_ws, size_t ws_size,
                              hipStream_t stream) {
    const float* query = (const float*)d_in[0];
    const float* align = (const float*)d_in[1];
    const float* P     = (const float*)d_in[2];
    const float* W_w   = (const float*)d_in[3];
    const float* W_b   = (const float*)d_in[4];
    const float* V_w   = (const float*)d_in[5];
    const float* F_w   = (const float*)d_in[6];
    const float* U_w   = (const float*)d_in[7];
    const float* T_w   = (const float*)d_in[8];
    const float* T_b   = (const float*)d_in[9];
    const float* v_w   = (const float*)d_in[10];
    float* out  = (float*)d_out;
    float* G_ws = (float*)d_ws;   // 256*168 floats

    g_kernel<<<Bsz, 512, 0, stream>>>(query, W_w, W_b, V_w, G_ws);
    e_kernel<<<Bsz, 1024, 0, stream>>>(align, P, F_w, U_w, T_w, T_b, v_w, G_ws, out);
}

// Round 4
// 123.435 us; speedup vs baseline: 1.9789x; 1.0744x over previous
//
#include <hip/hip_runtime.h>
#include <hip/hip_bf16.h>

#define Bsz 256
#define Tn 2048
#define QD 1024
#define AD 128
#define DCn 8
#define DKn 21
#define PLn 11
#define GN (DCn * DKn)   // 168
#define XS2 24           // Xw row stride in halfs (48 B; 16B-aligned rows)

typedef _Float16 f16x8 __attribute__((ext_vector_type(8)));
typedef float f32x4 __attribute__((ext_vector_type(4)));

// ---------------------------------------------------------------------------
// Kernel 1: per-sample dynamic filters  G[b] = tanh(q W^T + b) V^T  -> d_ws
// ---------------------------------------------------------------------------
__global__ __launch_bounds__(512) void g_kernel(
    const float* __restrict__ query, const float* __restrict__ W_w,
    const float* __restrict__ W_b, const float* __restrict__ V_w,
    float* __restrict__ G_ws)
{
    __shared__ float h_lds[AD];
    const int b    = blockIdx.x;
    const int tid  = threadIdx.x;
    const int w    = tid >> 6;      // 0..7
    const int lane = tid & 63;

    const float4* q4 = (const float4*)(query + b * QD);
    float4 q0 = q4[lane];
    float4 q1 = q4[64 + lane];
    float4 q2 = q4[128 + lane];
    float4 q3 = q4[192 + lane];

    #pragma unroll 2
    for (int i = 0; i < 16; ++i) {
        int a = w * 16 + i;
        const float4* w4 = (const float4*)(W_w + a * QD);
        float4 x0 = w4[lane];
        float4 x1 = w4[64 + lane];
        float4 x2 = w4[128 + lane];
        float4 x3 = w4[192 + lane];
        float accA = 0.f, accB = 0.f;
        accA = fmaf(q0.x, x0.x, fmaf(q0.y, x0.y, fmaf(q0.z, x0.z, fmaf(q0.w, x0.w, accA))));
        accB = fmaf(q1.x, x1.x, fmaf(q1.y, x1.y, fmaf(q1.z, x1.z, fmaf(q1.w, x1.w, accB))));
        accA = fmaf(q2.x, x2.x, fmaf(q2.y, x2.y, fmaf(q2.z, x2.z, fmaf(q2.w, x2.w, accA))));
        accB = fmaf(q3.x, x3.x, fmaf(q3.y, x3.y, fmaf(q3.z, x3.z, fmaf(q3.w, x3.w, accB))));
        float acc = accA + accB;
        #pragma unroll
        for (int off = 32; off; off >>= 1) acc += __shfl_xor(acc, off);
        if (lane == 0) h_lds[a] = tanhf(acc + W_b[a]);
    }
    __syncthreads();

    for (int r = w; r < GN; r += 8) {
        float acc = fmaf(h_lds[lane], V_w[r * AD + lane],
                         h_lds[64 + lane] * V_w[r * AD + 64 + lane]);
        #pragma unroll
        for (int off = 32; off; off >>= 1) acc += __shfl_xor(acc, off);
        if (lane == 0) G_ws[b * GN + r] = acc;
    }
}

// ---------------------------------------------------------------------------
// Kernel 2 (wave-local): per wave, 8 tiles of 16 t:
//   conv-MFMA (im2col A from f16 alignment row) -> X[16t x 16c]
//   -> wave-private LDS transpose (no block barrier, lgkmcnt only)
//   -> 8 proj MFMAs -> tanh*v reduce -> s = clip(prior)*exp(e_inner).
// Only 3 block barriers total (staging, prior, softmax sum).
// ---------------------------------------------------------------------------
__global__ __launch_bounds__(1024, 4) void e_kernel(
    const float* __restrict__ align, const float* __restrict__ P,
    const float* __restrict__ F_w, const float* __restrict__ U_w,
    const float* __restrict__ T_w, const float* __restrict__ T_b,
    const float* __restrict__ v_w, const float* __restrict__ G_ws,
    float* __restrict__ out)
{
    __shared__ float    al32[Tn + 20];
    __shared__ _Float16 al16[Tn + 44];       // padded tail for k up to 31
    __shared__ float    pcb[Tn];
    __shared__ float    sden[Tn];
    __shared__ _Float16 Xw[16 * 16 * XS2];   // per-wave 16x16 f16 tile, stride 24
    __shared__ float    red[16];
    __shared__ float    bc;

    const int b    = blockIdx.x;
    const int tid  = threadIdx.x;
    const int lane = tid & 63;
    const int wid  = tid >> 6;
    const int l15  = lane & 15;
    const int quad = lane >> 4;

    // ---- stage alignment row (fp32 for prior, f16 for conv A-frags) ----
    for (int i = tid; i < Tn + 44; i += 1024) {
        int s = i - 10;
        float v = (s >= 0 && s < Tn) ? align[b * Tn + s] : 0.f;
        if (i < Tn + 20) al32[i] = v;
        al16[i] = (_Float16)v;
    }

    // ---- conv B-frag: B[k=quad*8+j][n=c=l15] = W'[c][k], taps>=21 zero ----
    f16x8 Bc = {};
    #pragma unroll
    for (int j = 0; j < 8; ++j) {
        int k = quad * 8 + j;
        float wv = 0.f;
        if (k < DKn) wv = (l15 < 8) ? F_w[l15 * DKn + k]
                                    : G_ws[b * GN + (l15 - 8) * DKn + k];
        Bc[j] = (_Float16)wv;
    }

    // ---- proj B-frags (x2 pre-scale folds tanh's 2x into the GEMM) ----
    f16x8 Bf[8];
    float vv[8], tb[8];
    #pragma unroll
    for (int n = 0; n < 8; ++n) {
        int a = n * 16 + l15;
        f16x8 bf = {};
        const float* src = (quad == 0) ? (U_w + a * 8) : (T_w + a * 8);
        if (quad < 2) {
            float4 lo = ((const float4*)src)[0];
            float4 hi = ((const float4*)src)[1];
            bf[0] = (_Float16)(2.f * lo.x); bf[1] = (_Float16)(2.f * lo.y);
            bf[2] = (_Float16)(2.f * lo.z); bf[3] = (_Float16)(2.f * lo.w);
            bf[4] = (_Float16)(2.f * hi.x); bf[5] = (_Float16)(2.f * hi.y);
            bf[6] = (_Float16)(2.f * hi.z); bf[7] = (_Float16)(2.f * hi.w);
        }
        Bf[n] = bf;
        vv[n] = v_w[a];
        tb[n] = 2.f * T_b[a];
    }
    __syncthreads();

    // ---- prior (fp32), one t-pair per thread ----
    #pragma unroll
    for (int tt = 0; tt < 2; ++tt) {
        int t = tid + tt * 1024;
        float pr = 0.f;
        #pragma unroll
        for (int k = 0; k < PLn; ++k) pr = fmaf(al32[t + k], P[k], pr);
        pcb[t] = fmaxf(pr, 1e-6f);
    }
    __syncthreads();

    // ---- wave-local main loop: 8 tiles of 16 t per wave ----
    const int t0w = wid * 128;
    _Float16* Xp = &Xw[wid * 16 * XS2];
    float wsum = 0.f;

    for (int m = 0; m < 8; ++m) {
        const int t0 = t0w + m * 16;

        // conv A-frag: A[m=l15][k=quad*8+j] = al16[t0 + l15 + quad*8 + j]
        f16x8 Ac;
        #pragma unroll
        for (int j = 0; j < 8; ++j) Ac[j] = al16[t0 + l15 + quad * 8 + j];

        f32x4 z = {};
        f32x4 Xd = __builtin_amdgcn_mfma_f32_16x16x32_f16(Ac, Bc, z, 0, 0, 0);

        // D[m=t^=quad*4+r][n=c=l15] -> wave-private LDS tile [t^][c]
        #pragma unroll
        for (int r = 0; r < 4; ++r)
            Xp[(quad * 4 + r) * XS2 + l15] = (_Float16)Xd[r];

        // wave-sync: drain LDS writes before cross-lane reads (no s_barrier)
        asm volatile("s_waitcnt lgkmcnt(0)" ::: "memory");

        // proj A-frag: A2[m=t^=l15][k=c=quad*8+j], K=16 real (quads 2,3 zero)
        f16x8 A2 = {};
        if (quad < 2) A2 = *(const f16x8*)&Xp[l15 * XS2 + quad * 8];

        float es0 = 0.f, es1 = 0.f, es2 = 0.f, es3 = 0.f;
        #pragma unroll
        for (int n = 0; n < 8; ++n) {
            f32x4 z2 = {};
            f32x4 d = __builtin_amdgcn_mfma_f32_16x16x32_f16(A2, Bf[n], z2, 0, 0, 0);
            // d + tb == 2*(Ux+Tg+b); tanh(x) = 1 - 2/(exp(2x)+1)
            float q0 = __expf(d[0] + tb[n]);
            float q1 = __expf(d[1] + tb[n]);
            float q2 = __expf(d[2] + tb[n]);
            float q3 = __expf(d[3] + tb[n]);
            float r0 = __builtin_amdgcn_rcpf(q0 + 1.f);
            float r1 = __builtin_amdgcn_rcpf(q1 + 1.f);
            float r2 = __builtin_amdgcn_rcpf(q2 + 1.f);
            float r3 = __builtin_amdgcn_rcpf(q3 + 1.f);
            es0 = fmaf(vv[n], fmaf(-2.f, r0, 1.f), es0);
            es1 = fmaf(vv[n], fmaf(-2.f, r1, 1.f), es1);
            es2 = fmaf(vv[n], fmaf(-2.f, r2, 1.f), es2);
            es3 = fmaf(vv[n], fmaf(-2.f, r3, 1.f), es3);
        }
        // reduce over the 16 a-cols (l15 group)
        #pragma unroll
        for (int off = 1; off <= 8; off <<= 1) {
            es0 += __shfl_xor(es0, off);
            es1 += __shfl_xor(es1, off);
            es2 += __shfl_xor(es2, off);
            es3 += __shfl_xor(es3, off);
        }
        if (l15 < 4) {
            float ev = (l15 == 0) ? es0 : (l15 == 1) ? es1 : (l15 == 2) ? es2 : es3;
            int t = t0 + quad * 4 + l15;
            float sv = pcb[t] * __expf(ev);
            sden[t] = sv;
            wsum += sv;
        }
    }

    // ---- block sum + normalize ----
    __syncthreads();
    #pragma unroll
    for (int off = 32; off; off >>= 1) wsum += __shfl_xor(wsum, off);
    if (lane == 0) red[wid] = wsum;
    __syncthreads();
    if (wid == 0) {
        float ss = (lane < 16) ? red[lane] : 0.f;
        #pragma unroll
        for (int off = 8; off; off >>= 1) ss += __shfl_xor(ss, off);
        if (lane == 0) bc = ss;
    }
    __syncthreads();
    const float inv = 1.f / bc;
    out[b * Tn + tid]        = sden[tid] * inv;
    out[b * Tn + tid + 1024] = sden[tid + 1024] * inv;
}

// ---------------------------------------------------------------------------
extern "C" void kernel_launch(void* const* d_in, const int* in_sizes, int n_in,
                              void* d_out, int out_size, void* d_ws, size_t ws_size,
                              hipStream_t stream) {
    const float* query = (const float*)d_in[0];
    const float* align = (const float*)d_in[1];
    const float* P     = (const float*)d_in[2];
    const float* W_w   = (const float*)d_in[3];
    const float* W_b   = (const float*)d_in[4];
    const float* V_w   = (const float*)d_in[5];
    const float* F_w   = (const float*)d_in[6];
    const float* U_w   = (const float*)d_in[7];
    const float* T_w   = (const float*)d_in[8];
    const float* T_b   = (const float*)d_in[9];
    const float* v_w   = (const float*)d_in[10];
    float* out  = (float*)d_out;
    float* G_ws = (float*)d_ws;   // 256*168 floats

    g_kernel<<<Bsz, 512, 0, stream>>>(query, W_w, W_b, V_w, G_ws);
    e_kernel<<<Bsz, 1024, 0, stream>>>(align, P, F_w, U_w, T_w, T_b, v_w, G_ws, out);
}

// Round 5
// 120.053 us; speedup vs baseline: 2.0347x; 1.0282x over previous
//
#include <hip/hip_runtime.h>
#include <hip/hip_bf16.h>

#define Bsz 256
#define Tn 2048
#define QD 1024
#define AD 128
#define DCn 8
#define DKn 21
#define PLn 11
#define GN (DCn * DKn)   // 168
#define XS2 24           // X row stride in halfs (48 B; rows 16B-aligned)

typedef _Float16 f16x8 __attribute__((ext_vector_type(8)));
typedef float f32x4 __attribute__((ext_vector_type(4)));

#define TWO_LOG2E 2.8853900817779268f   // 2*log2(e): folds tanh's 2x and exp->exp2

// ---------------------------------------------------------------------------
// Kernel 1: per-sample dynamic filters  G[b] = tanh(q W^T + b) V^T  -> d_ws
// ---------------------------------------------------------------------------
__global__ __launch_bounds__(512) void g_kernel(
    const float* __restrict__ query, const float* __restrict__ W_w,
    const float* __restrict__ W_b, const float* __restrict__ V_w,
    float* __restrict__ G_ws)
{
    __shared__ float h_lds[AD];
    const int b    = blockIdx.x;
    const int tid  = threadIdx.x;
    const int w    = tid >> 6;      // 0..7
    const int lane = tid & 63;

    const float4* q4 = (const float4*)(query + b * QD);
    float4 q0 = q4[lane];
    float4 q1 = q4[64 + lane];
    float4 q2 = q4[128 + lane];
    float4 q3 = q4[192 + lane];

    #pragma unroll 2
    for (int i = 0; i < 16; ++i) {
        int a = w * 16 + i;
        const float4* w4 = (const float4*)(W_w + a * QD);
        float4 x0 = w4[lane];
        float4 x1 = w4[64 + lane];
        float4 x2 = w4[128 + lane];
        float4 x3 = w4[192 + lane];
        float accA = 0.f, accB = 0.f;
        accA = fmaf(q0.x, x0.x, fmaf(q0.y, x0.y, fmaf(q0.z, x0.z, fmaf(q0.w, x0.w, accA))));
        accB = fmaf(q1.x, x1.x, fmaf(q1.y, x1.y, fmaf(q1.z, x1.z, fmaf(q1.w, x1.w, accB))));
        accA = fmaf(q2.x, x2.x, fmaf(q2.y, x2.y, fmaf(q2.z, x2.z, fmaf(q2.w, x2.w, accA))));
        accB = fmaf(q3.x, x3.x, fmaf(q3.y, x3.y, fmaf(q3.z, x3.z, fmaf(q3.w, x3.w, accB))));
        float acc = accA + accB;
        #pragma unroll
        for (int off = 32; off; off >>= 1) acc += __shfl_xor(acc, off);
        if (lane == 0) h_lds[a] = tanhf(acc + W_b[a]);
    }
    __syncthreads();

    for (int r = w; r < GN; r += 8) {
        float acc = fmaf(h_lds[lane], V_w[r * AD + lane],
                         h_lds[64 + lane] * V_w[r * AD + 64 + lane]);
        #pragma unroll
        for (int off = 32; off; off >>= 1) acc += __shfl_xor(acc, off);
        if (lane == 0) G_ws[b * GN + r] = acc;
    }
}

// ---------------------------------------------------------------------------
// Kernel 2 (wave-local, 2-tile pipelined): per wave, 4 iters of 2x16 t:
//   2x conv-MFMA (im2col) -> 2 wave-private LDS transposes (no barrier,
//   DS in-order per wave; compiler emits its own fine lgkmcnt) -> 2x8 proj
//   MFMAs -> interleaved tanh*v reduce -> s = clip(prior)*exp(e_inner).
// tanh folds: B-frags pre-scaled by 2*log2e so q=exp2(d+tb)=exp(2x);
// es accumulates -2*vv*rcp(q+1); +Sum(vv) added once post-reduce.
// ---------------------------------------------------------------------------
__global__ __launch_bounds__(1024, 4) void e_kernel(
    const float* __restrict__ align, const float* __restrict__ P,
    const float* __restrict__ F_w, const float* __restrict__ U_w,
    const float* __restrict__ T_w, const float* __restrict__ T_b,
    const float* __restrict__ v_w, const float* __restrict__ G_ws,
    float* __restrict__ out)
{
    __shared__ float    al32[Tn + 20];
    __shared__ _Float16 al16[Tn + 44];
    __shared__ float    pcb[Tn];
    __shared__ float    sden[Tn];
    __shared__ _Float16 Xw[16 * 2 * 16 * XS2];  // 2 tiles/wave, 16 waves
    __shared__ float    red[16];
    __shared__ float    bc;

    const int b    = blockIdx.x;
    const int tid  = threadIdx.x;
    const int lane = tid & 63;
    const int wid  = tid >> 6;
    const int l15  = lane & 15;
    const int quad = lane >> 4;

    // ---- stage alignment row (fp32 for prior, f16 for conv A-frags) ----
    for (int i = tid; i < Tn + 44; i += 1024) {
        int s = i - 10;
        float v = (s >= 0 && s < Tn) ? align[b * Tn + s] : 0.f;
        if (i < Tn + 20) al32[i] = v;
        al16[i] = (_Float16)v;
    }

    // ---- conv B-frag: B[k=quad*8+j][n=c=l15] = W'[c][k], taps>=21 zero ----
    f16x8 Bc = {};
    #pragma unroll
    for (int j = 0; j < 8; ++j) {
        int k = quad * 8 + j;
        float wv = 0.f;
        if (k < DKn) wv = (l15 < 8) ? F_w[l15 * DKn + k]
                                    : G_ws[b * GN + (l15 - 8) * DKn + k];
        Bc[j] = (_Float16)wv;
    }

    // ---- proj B-frags (x TWO_LOG2E pre-scale) + epilogue constants ----
    f16x8 Bf[8];
    float vn2[8], tb2[8];
    float vsum = 0.f;
    #pragma unroll
    for (int n = 0; n < 8; ++n) {
        int a = n * 16 + l15;
        f16x8 bf = {};
        const float* src = (quad == 0) ? (U_w + a * 8) : (T_w + a * 8);
        if (quad < 2) {
            float4 lo = ((const float4*)src)[0];
            float4 hi = ((const float4*)src)[1];
            bf[0] = (_Float16)(TWO_LOG2E * lo.x); bf[1] = (_Float16)(TWO_LOG2E * lo.y);
            bf[2] = (_Float16)(TWO_LOG2E * lo.z); bf[3] = (_Float16)(TWO_LOG2E * lo.w);
            bf[4] = (_Float16)(TWO_LOG2E * hi.x); bf[5] = (_Float16)(TWO_LOG2E * hi.y);
            bf[6] = (_Float16)(TWO_LOG2E * hi.z); bf[7] = (_Float16)(TWO_LOG2E * hi.w);
        }
        Bf[n] = bf;
        float va = v_w[a];
        vn2[n] = -2.f * va;
        vsum  += va;
        tb2[n] = TWO_LOG2E * T_b[a];
    }
    // vsum over this lane's 8 a's -> full sum over 128 a's (16-lane group)
    #pragma unroll
    for (int off = 1; off <= 8; off <<= 1) vsum += __shfl_xor(vsum, off);
    __syncthreads();

    // ---- prior (fp32), one t-pair per thread ----
    #pragma unroll
    for (int tt = 0; tt < 2; ++tt) {
        int t = tid + tt * 1024;
        float pr = 0.f;
        #pragma unroll
        for (int k = 0; k < PLn; ++k) pr = fmaf(al32[t + k], P[k], pr);
        pcb[t] = fmaxf(pr, 1e-6f);
    }
    __syncthreads();

    // ---- wave-local main loop: 4 iterations of 2 tiles (32 t) ----
    const int t0w = wid * 128;
    _Float16* Xp0 = &Xw[wid * 2 * 16 * XS2];
    _Float16* Xp1 = Xp0 + 16 * XS2;
    float wsum = 0.f;

    #pragma unroll 1
    for (int m = 0; m < 8; m += 2) {
        const int ta = t0w + m * 16;
        const int tb_ = ta + 16;

        // conv A-frags for both tiles: A[m=l15][k=quad*8+j]
        f16x8 Ac0, Ac1;
        #pragma unroll
        for (int j = 0; j < 8; ++j) {
            Ac0[j] = al16[ta  + l15 + quad * 8 + j];
            Ac1[j] = al16[tb_ + l15 + quad * 8 + j];
        }
        f32x4 z = {};
        f32x4 X0 = __builtin_amdgcn_mfma_f32_16x16x32_f16(Ac0, Bc, z, 0, 0, 0);
        f32x4 X1 = __builtin_amdgcn_mfma_f32_16x16x32_f16(Ac1, Bc, z, 0, 0, 0);

        // D[m=t^][n=c] -> wave-private LDS tiles (t^ = quad*4+r, c = l15)
        #pragma unroll
        for (int r = 0; r < 4; ++r) {
            Xp0[(quad * 4 + r) * XS2 + l15] = (_Float16)X0[r];
            Xp1[(quad * 4 + r) * XS2 + l15] = (_Float16)X1[r];
        }
        // same-wave DS RAW: DS ops process in order per wave; compiler's own
        // lgkmcnt before the A2-consuming MFMA covers it. Keep compile order:
        __asm__ __volatile__("" ::: "memory");

        // proj A-frags: A2[m=t^=l15][k=c=quad*8+j], K=16 real
        f16x8 A20 = {}, A21 = {};
        if (quad < 2) {
            A20 = *(const f16x8*)&Xp0[l15 * XS2 + quad * 8];
            A21 = *(const f16x8*)&Xp1[l15 * XS2 + quad * 8];
        }

        float esA[4] = {0.f, 0.f, 0.f, 0.f};
        float esB[4] = {0.f, 0.f, 0.f, 0.f};
        #pragma unroll
        for (int n = 0; n < 8; ++n) {
            f32x4 z2 = {};
            f32x4 d0 = __builtin_amdgcn_mfma_f32_16x16x32_f16(A20, Bf[n], z2, 0, 0, 0);
            f32x4 d1 = __builtin_amdgcn_mfma_f32_16x16x32_f16(A21, Bf[n], z2, 0, 0, 0);
            #pragma unroll
            for (int r = 0; r < 4; ++r) {
                float qa = __builtin_amdgcn_exp2f(d0[r] + tb2[n]);
                float qb = __builtin_amdgcn_exp2f(d1[r] + tb2[n]);
                float ra = __builtin_amdgcn_rcpf(qa + 1.f);
                float rb = __builtin_amdgcn_rcpf(qb + 1.f);
                esA[r] = fmaf(vn2[n], ra, esA[r]);
                esB[r] = fmaf(vn2[n], rb, esB[r]);
            }
        }
        // reduce over the 16 a-cols (xor within 16-lane group)
        #pragma unroll
        for (int off = 1; off <= 8; off <<= 1) {
            #pragma unroll
            for (int r = 0; r < 4; ++r) {
                esA[r] += __shfl_xor(esA[r], off);
                esB[r] += __shfl_xor(esB[r], off);
            }
        }
        if (l15 < 4) {
            float evA = ((l15 == 0) ? esA[0] : (l15 == 1) ? esA[1]
                       : (l15 == 2) ? esA[2] : esA[3]) + vsum;
            float evB = ((l15 == 0) ? esB[0] : (l15 == 1) ? esB[1]
                       : (l15 == 2) ? esB[2] : esB[3]) + vsum;
            int tA = ta  + quad * 4 + l15;
            int tB = tb_ + quad * 4 + l15;
            float svA = pcb[tA] * __expf(evA);
            float svB = pcb[tB] * __expf(evB);
            sden[tA] = svA;
            sden[tB] = svB;
            wsum += svA + svB;
        }
    }

    // ---- block sum + normalize ----
    __syncthreads();
    #pragma unroll
    for (int off = 32; off; off >>= 1) wsum += __shfl_xor(wsum, off);
    if (lane == 0) red[wid] = wsum;
    __syncthreads();
    if (wid == 0) {
        float ss = (lane < 16) ? red[lane] : 0.f;
        #pragma unroll
        for (int off = 8; off; off >>= 1) ss += __shfl_xor(ss, off);
        if (lane == 0) bc = ss;
    }
    __syncthreads();
    const float inv = 1.f / bc;
    out[b * Tn + tid]        = sden[tid] * inv;
    out[b * Tn + tid + 1024] = sden[tid + 1024] * inv;
}

// ---------------------------------------------------------------------------
extern "C" void kernel_launch(void* const* d_in, const int* in_sizes, int n_in,
                              void* d_out, int out_size, void* d_ws, size_t ws_size,
                              hipStream_t stream) {
    const float* query = (const float*)d_in[0];
    const float* align = (const float*)d_in[1];
    const float* P     = (const float*)d_in[2];
    const float* W_w   = (const float*)d_in[3];
    const float* W_b   = (const float*)d_in[4];
    const float* V_w   = (const float*)d_in[5];
    const float* F_w   = (const float*)d_in[6];
    const float* U_w   = (const float*)d_in[7];
    const float* T_w   = (const float*)d_in[8];
    const float* T_b   = (const float*)d_in[9];
    const float* v_w   = (const float*)d_in[10];
    float* out  = (float*)d_out;
    float* G_ws = (float*)d_ws;   // 256*168 floats

    g_kernel<<<Bsz, 512, 0, stream>>>(query, W_w, W_b, V_w, G_ws);
    e_kernel<<<Bsz, 1024, 0, stream>>>(align, P, F_w, U_w, T_w, T_b, v_w, G_ws, out);
}

// Round 6
// 105.976 us; speedup vs baseline: 2.3049x; 1.1328x over previous
//
#include <hip/hip_runtime.h>
#include <hip/hip_bf16.h>

#define Bsz 256
#define Tn 2048
#define QD 1024
#define AD 128
#define DCn 8
#define DKn 21
#define PLn 11
#define GN (DCn * DKn)   // 168
#define XS2 24           // X row stride in halfs (48 B; rows 16B-aligned)

typedef _Float16 f16x8 __attribute__((ext_vector_type(8)));
typedef float f32x4 __attribute__((ext_vector_type(4)));

#define TWO_LOG2E 2.8853900817779268f   // 2*log2(e): folds tanh's 2x and exp->exp2

// ---------------------------------------------------------------------------
// Single fused kernel. Per b (one 1024-thread block):
//   [g-phase]  h = tanh(W_w q + W_b) (overlaps al16 staging latency),
//              G = V_w h -> LDS
//   [prior]    pcb[t] = clip(conv(al, P)) wave-locally (no extra barrier)
//   [main]     per wave, 4 iters x 2 tiles of 16 t, zero block barriers:
//              conv-MFMA (im2col) -> wave-private LDS transpose ->
//              proj-MFMA SWAPPED: d = mfma(Wfrag, Xfrag) = y^T[a][t]
//              (row=a_local=quad*4+r, col=t=l15) -> tanh via exp2/rcp with
//              in-lane v-weights vn2q[n][r] -> reduce over quads = 2 shuffles
//              (replaces R5's 32-swizzle tree). Bias rides the k=16 channel.
//   [softmax]  s = pcb * exp(e_inner); block sum; normalize.
// ---------------------------------------------------------------------------
__global__ __launch_bounds__(1024, 4) void dca_kernel(
    const float* __restrict__ query, const float* __restrict__ align,
    const float* __restrict__ P, const float* __restrict__ W_w,
    const float* __restrict__ W_b, const float* __restrict__ V_w,
    const float* __restrict__ F_w, const float* __restrict__ U_w,
    const float* __restrict__ T_w, const float* __restrict__ T_b,
    const float* __restrict__ v_w, float* __restrict__ out)
{
    __shared__ _Float16 al16[Tn + 44];
    __shared__ float    pcb[Tn];
    __shared__ float    sden[Tn];
    __shared__ _Float16 Xw[16 * 2 * 16 * XS2];  // 2 tiles/wave, 16 waves
    __shared__ float    h_lds[AD];
    __shared__ float    G_lds[GN];
    __shared__ float    red[16];
    __shared__ float    bc;

    const int b    = blockIdx.x;
    const int tid  = threadIdx.x;
    const int lane = tid & 63;
    const int wid  = tid >> 6;
    const int l15  = lane & 15;
    const int quad = lane >> 4;

    // ---- stage alignment row as f16 (pad=10 each side; index i ~ t=i-10) ----
    for (int i = tid; i < Tn + 44; i += 1024) {
        int s = i - 10;
        float v = (s >= 0 && s < Tn) ? align[b * Tn + s] : 0.f;
        al16[i] = (_Float16)v;
    }

    // ---- g-phase 1: h = tanh(W_w q + W_b); wave handles 8 a-rows ----
    {
        const float4* q4 = (const float4*)(query + b * QD);
        float4 q0 = q4[lane];
        float4 q1 = q4[64 + lane];
        float4 q2 = q4[128 + lane];
        float4 q3 = q4[192 + lane];
        #pragma unroll 2
        for (int i = 0; i < 8; ++i) {
            int a = wid * 8 + i;
            const float4* w4 = (const float4*)(W_w + a * QD);
            float4 x0 = w4[lane];
            float4 x1 = w4[64 + lane];
            float4 x2 = w4[128 + lane];
            float4 x3 = w4[192 + lane];
            float accA = 0.f, accB = 0.f;
            accA = fmaf(q0.x, x0.x, fmaf(q0.y, x0.y, fmaf(q0.z, x0.z, fmaf(q0.w, x0.w, accA))));
            accB = fmaf(q1.x, x1.x, fmaf(q1.y, x1.y, fmaf(q1.z, x1.z, fmaf(q1.w, x1.w, accB))));
            accA = fmaf(q2.x, x2.x, fmaf(q2.y, x2.y, fmaf(q2.z, x2.z, fmaf(q2.w, x2.w, accA))));
            accB = fmaf(q3.x, x3.x, fmaf(q3.y, x3.y, fmaf(q3.z, x3.z, fmaf(q3.w, x3.w, accB))));
            float acc = accA + accB;
            #pragma unroll
            for (int off = 32; off; off >>= 1) acc += __shfl_xor(acc, off);
            if (lane == 0) h_lds[a] = tanhf(acc + W_b[a]);
        }
    }
    __syncthreads();   // h_lds + al16 ready

    // ---- g-phase 2: G = V_w h (168 rows, one thread each) ----
    if (tid < GN) {
        float g = 0.f;
        #pragma unroll 4
        for (int i = 0; i < AD; ++i) g = fmaf(h_lds[i], V_w[tid * AD + i], g);
        G_lds[tid] = g;
    }

    // ---- prior, wave-local (same wave writes & reads its pcb range) ----
    const int t0w = wid * 128;
    #pragma unroll
    for (int tt = 0; tt < 2; ++tt) {
        int t = t0w + tt * 64 + lane;
        float pr = 0.f;
        #pragma unroll
        for (int k = 0; k < PLn; ++k) pr = fmaf((float)al16[t + k], P[k], pr);
        pcb[t] = fmaxf(pr, 1e-6f);
    }
    __syncthreads();   // G_lds ready

    // ---- conv B-frag: B[k=quad*8+j][n=c=l15] = W'[c][k], taps>=21 zero ----
    f16x8 Bc = {};
    #pragma unroll
    for (int j = 0; j < 8; ++j) {
        int k = quad * 8 + j;
        float wv = 0.f;
        if (k < DKn) wv = (l15 < 8) ? F_w[l15 * DKn + k]
                                    : G_lds[(l15 - 8) * DKn + k];
        Bc[j] = (_Float16)wv;
    }

    // ---- proj weight frags (used as MFMA *A* operand: A[m=a_loc=l15][k]) ----
    // k=0..7: U (f-channels), k=8..15: T (g-channels), k=16: bias channel.
    f16x8 Bf[8];
    #pragma unroll
    for (int n = 0; n < 8; ++n) {
        int a = n * 16 + l15;
        f16x8 bf = {};
        if (quad < 2) {
            const float* src = (quad == 0) ? (U_w + a * 8) : (T_w + a * 8);
            float4 lo = ((const float4*)src)[0];
            float4 hi = ((const float4*)src)[1];
            bf[0] = (_Float16)(TWO_LOG2E * lo.x); bf[1] = (_Float16)(TWO_LOG2E * lo.y);
            bf[2] = (_Float16)(TWO_LOG2E * lo.z); bf[3] = (_Float16)(TWO_LOG2E * lo.w);
            bf[4] = (_Float16)(TWO_LOG2E * hi.x); bf[5] = (_Float16)(TWO_LOG2E * hi.y);
            bf[6] = (_Float16)(TWO_LOG2E * hi.z); bf[7] = (_Float16)(TWO_LOG2E * hi.w);
        } else if (quad == 2) {
            bf[0] = (_Float16)(TWO_LOG2E * T_b[a]);   // k=16 bias channel
        }
        Bf[n] = bf;
    }

    // ---- in-lane v-weights: vn2q[n][r] = -2*v_w[n*16 + quad*4 + r] ----
    f32x4 vnq[8];
    float vsum = 0.f;
    #pragma unroll
    for (int n = 0; n < 8; ++n) {
        f32x4 vq = *(const f32x4*)(v_w + n * 16 + quad * 4);
        vsum += vq[0] + vq[1] + vq[2] + vq[3];
        vq[0] *= -2.f; vq[1] *= -2.f; vq[2] *= -2.f; vq[3] *= -2.f;
        vnq[n] = vq;
    }
    vsum += __shfl_xor(vsum, 16);
    vsum += __shfl_xor(vsum, 32);   // full sum over 128 a's

    // ---- wave-local main loop: 4 iterations of 2 tiles (32 t) ----
    _Float16* Xp0 = &Xw[wid * 2 * 16 * XS2];
    _Float16* Xp1 = Xp0 + 16 * XS2;
    float wsum = 0.f;

    #pragma unroll 1
    for (int m = 0; m < 8; m += 2) {
        const int ta  = t0w + m * 16;
        const int tb_ = ta + 16;

        // conv A-frags: A[m=t_loc=l15][k=tap=quad*8+j]
        f16x8 Ac0, Ac1;
        #pragma unroll
        for (int j = 0; j < 8; ++j) {
            Ac0[j] = al16[ta  + l15 + quad * 8 + j];
            Ac1[j] = al16[tb_ + l15 + quad * 8 + j];
        }
        f32x4 z = {};
        f32x4 X0 = __builtin_amdgcn_mfma_f32_16x16x32_f16(Ac0, Bc, z, 0, 0, 0);
        f32x4 X1 = __builtin_amdgcn_mfma_f32_16x16x32_f16(Ac1, Bc, z, 0, 0, 0);

        // D[m=t_loc=quad*4+r][n=c=l15] -> wave-private LDS tiles [t_loc][c]
        #pragma unroll
        for (int r = 0; r < 4; ++r) {
            Xp0[(quad * 4 + r) * XS2 + l15] = (_Float16)X0[r];
            Xp1[(quad * 4 + r) * XS2 + l15] = (_Float16)X1[r];
        }
        __asm__ __volatile__("" ::: "memory");  // keep order; HW DS is in-order/wave

        // X^T frags (MFMA *B* operand): B[k=c=quad*8+j][n=t_loc=l15];
        // k=16 (quad2,j0) = 1.0 feeds the bias channel.
        f16x8 B20 = {}, B21 = {};
        if (quad < 2) {
            B20 = *(const f16x8*)&Xp0[l15 * XS2 + quad * 8];
            B21 = *(const f16x8*)&Xp1[l15 * XS2 + quad * 8];
        } else if (quad == 2) {
            B20[0] = (_Float16)1.f;
            B21[0] = (_Float16)1.f;
        }

        float es0 = 0.f, es1 = 0.f;
        #pragma unroll
        for (int n = 0; n < 8; ++n) {
            f32x4 z2 = {};
            // swapped operands: D[m=a_loc][n=t]: row=a_loc=quad*4+r, col=t=l15
            f32x4 d0 = __builtin_amdgcn_mfma_f32_16x16x32_f16(Bf[n], B20, z2, 0, 0, 0);
            f32x4 d1 = __builtin_amdgcn_mfma_f32_16x16x32_f16(Bf[n], B21, z2, 0, 0, 0);
            #pragma unroll
            for (int r = 0; r < 4; ++r) {
                float qa = __builtin_amdgcn_exp2f(d0[r]);
                float qb = __builtin_amdgcn_exp2f(d1[r]);
                float ra = __builtin_amdgcn_rcpf(qa + 1.f);
                float rb = __builtin_amdgcn_rcpf(qb + 1.f);
                es0 = fmaf(vnq[n][r], ra, es0);
                es1 = fmaf(vnq[n][r], rb, es1);
            }
        }
        // full a-reduction: only across quads now (t = l15 is the lane col)
        es0 += __shfl_xor(es0, 16);
        es0 += __shfl_xor(es0, 32);
        es1 += __shfl_xor(es1, 16);
        es1 += __shfl_xor(es1, 32);

        if (lane < 16) {
            int tA = ta  + lane;
            int tB = tb_ + lane;
            float svA = pcb[tA] * __expf(es0 + vsum);
            float svB = pcb[tB] * __expf(es1 + vsum);
            sden[tA] = svA;
            sden[tB] = svB;
            wsum += svA + svB;
        }
    }

    // ---- block sum + normalize ----
    __syncthreads();
    #pragma unroll
    for (int off = 32; off; off >>= 1) wsum += __shfl_xor(wsum, off);
    if (lane == 0) red[wid] = wsum;
    __syncthreads();
    if (wid == 0) {
        float ss = (lane < 16) ? red[lane] : 0.f;
        #pragma unroll
        for (int off = 8; off; off >>= 1) ss += __shfl_xor(ss, off);
        if (lane == 0) bc = ss;
    }
    __syncthreads();
    const float inv = 1.f / bc;
    out[b * Tn + tid]        = sden[tid] * inv;
    out[b * Tn + tid + 1024] = sden[tid + 1024] * inv;
}

// ---------------------------------------------------------------------------
extern "C" void kernel_launch(void* const* d_in, const int* in_sizes, int n_in,
                              void* d_out, int out_size, void* d_ws, size_t ws_size,
                              hipStream_t stream) {
    const float* query = (const float*)d_in[0];
    const float* align = (const float*)d_in[1];
    const float* P     = (const float*)d_in[2];
    const float* W_w   = (const float*)d_in[3];
    const float* W_b   = (const float*)d_in[4];
    const float* V_w   = (const float*)d_in[5];
    const float* F_w   = (const float*)d_in[6];
    const float* U_w   = (const float*)d_in[7];
    const float* T_w   = (const float*)d_in[8];
    const float* T_b   = (const float*)d_in[9];
    const float* v_w   = (const float*)d_in[10];
    float* out = (float*)d_out;

    dca_kernel<<<Bsz, 1024, 0, stream>>>(query, align, P, W_w, W_b, V_w,
                                         F_w, U_w, T_w, T_b, v_w, out);
}